// Round 2
// baseline (5314.199 us; speedup 1.0000x reference)
//
#include <hip/hip_runtime.h>
#include <math.h>

// ---------------------------------------------------------------------------
// SimpleLESS4FDModel: 2-layer HGT on a homogeneous graph.
// Key algebraic simplification: a_rel / m_rel are per-head linear transforms of
// k / v, so we fold them into the projection weights:
//   kt = h @ (Wk . blockdiag(a_rel)) + bk . blockdiag(a_rel)
//   vt = h @ (Wv . blockdiag(m_rel)) + bv . blockdiag(m_rel)
// Then per edge:  alpha = <kt[src], q[dst]>_head * p_rel / 4 ;
//   agg[dst] = sum_e exp(alpha) * vt[src] / (sum_e exp(alpha) + 1e-16)
// (no max-subtraction needed: |alpha| << 1; mathematically identical ratio)
// CSR (built once, reused by both layers) makes aggregation atomic-free.
//
// R1 lesson: NEVER index a local array with a runtime value — vv[jj] forced
// scratch allocation (1.1 GB of spill writes per dispatch, VALUBusy 4.6%).
// All local arrays below are indexed by compile-time constants only.
// ---------------------------------------------------------------------------

__device__ __forceinline__ float gelu_t(float x) {
  const float c = 0.7978845608028654f;  // sqrt(2/pi)
  float t = tanhf(c * (x + 0.044715f * x * x * x));
  return 0.5f * x * (1.0f + t);
}

// ---------------- tiled GEMM: 128 rows x 64 cols per block --------------------
// out[r, colBlk+c] = epi(A[r,:]@W[:,colBlk+c] + bias[colBlk+c])
// PRE_GELU: apply gelu to A elements when staging. EPI_SKIP: skip-mix + relu.
template<int K, bool PRE_GELU, bool EPI_SKIP>
__global__ __launch_bounds__(256)
void gemm_tile(const float* __restrict__ A, int ldA,
               const float* __restrict__ W, int ldW,
               const float* __restrict__ bias,
               const float* __restrict__ Hprev,
               const float* __restrict__ skipPtr,
               float* __restrict__ outp, int ldOut,
               int nRows)
{
  __shared__ float sA[64][132];  // [k][row] transposed; stride 132 keeps 16B align
  __shared__ float sB[64][68];   // [k][col]
  const int tid = threadIdx.x;
  const int ty = tid >> 4, tx = tid & 15;  // ty: 8 rows each, tx: 4 cols each
  const int row0 = blockIdx.x * 128;
  const int colBlk = blockIdx.y * 64;
  float acc[8][4];
#pragma unroll
  for (int i = 0; i < 8; ++i)
#pragma unroll
    for (int j = 0; j < 4; ++j) acc[i][j] = 0.f;

  for (int kc = 0; kc < K; kc += 64) {
    // stage A chunk (128 rows x 64 k), transposed into sA[k][row].
    // Constant-index stores only (dynamic index => scratch spill, see R1).
    // ~8-way bank conflict on these ds_write_b32 is accepted: measured cost
    // is ~600K cycles chip-wide, negligible.
#pragma unroll
    for (int i = 0; i < 8; ++i) {
      int linear = i * 256 + tid;
      int r = linear >> 4;
      int k4 = (linear & 15) << 2;
      int gr = row0 + r;
      float4 v = make_float4(0.f, 0.f, 0.f, 0.f);
      if (gr < nRows) v = *(const float4*)(A + (size_t)gr * ldA + kc + k4);
      if (PRE_GELU) { v.x = gelu_t(v.x); v.y = gelu_t(v.y); v.z = gelu_t(v.z); v.w = gelu_t(v.w); }
      sA[k4 + 0][r] = v.x;
      sA[k4 + 1][r] = v.y;
      sA[k4 + 2][r] = v.z;
      sA[k4 + 3][r] = v.w;
    }
    // stage W chunk (64 k x 64 cols)
#pragma unroll
    for (int i = 0; i < 4; ++i) {
      int linear = i * 256 + tid;
      int kk = linear >> 4;
      int c4 = (linear & 15) << 2;
      *(float4*)&sB[kk][c4] = *(const float4*)(W + (size_t)(kc + kk) * ldW + colBlk + c4);
    }
    __syncthreads();
#pragma unroll
    for (int k = 0; k < 64; ++k) {
      float4 b4 = *(const float4*)&sB[k][tx << 2];
      float4 a0 = *(const float4*)&sA[k][ty << 3];
      float4 a1 = *(const float4*)&sA[k][(ty << 3) + 4];
      float aa[8] = {a0.x, a0.y, a0.z, a0.w, a1.x, a1.y, a1.z, a1.w};
      float bb[4] = {b4.x, b4.y, b4.z, b4.w};
#pragma unroll
      for (int i = 0; i < 8; ++i)
#pragma unroll
        for (int j = 0; j < 4; ++j)
          acc[i][j] = fmaf(aa[i], bb[j], acc[i][j]);
    }
    __syncthreads();
  }

  float g = 0.f, gi = 0.f;
  if (EPI_SKIP) { g = 1.0f / (1.0f + __expf(-skipPtr[0])); gi = 1.0f - g; }
  float4 bia = *(const float4*)(bias + colBlk + (tx << 2));
  float bb[4] = {bia.x, bia.y, bia.z, bia.w};
#pragma unroll
  for (int i = 0; i < 8; ++i) {
    int r = row0 + (ty << 3) + i;
    if (r < nRows) {
      float o[4];
#pragma unroll
      for (int j = 0; j < 4; ++j) o[j] = acc[i][j] + bb[j];
      if (EPI_SKIP) {
        float4 hp = *(const float4*)(Hprev + (size_t)r * 64 + (tx << 2));
        float hh[4] = {hp.x, hp.y, hp.z, hp.w};
#pragma unroll
        for (int j = 0; j < 4; ++j) o[j] = fmaxf(g * o[j] + gi * hh[j], 0.f);
      }
      float4 ov = make_float4(o[0], o[1], o[2], o[3]);
      *(float4*)(outp + (size_t)r * ldOut + colBlk + (tx << 2)) = ov;
    }
  }
}

// ---------------- fold a_rel / m_rel into packed qkv weights ------------------
// Wqkv[l]: [64][192]  cols 0..63 = Wq, 64..127 = Wk@BD(a_rel), 128..191 = Wv@BD(m_rel)
__global__ void fold_weights(const float* __restrict__ Wq, const float* __restrict__ bq,
                             const float* __restrict__ Wk, const float* __restrict__ bk,
                             const float* __restrict__ Wv, const float* __restrict__ bv,
                             const float* __restrict__ a_rel, const float* __restrict__ m_rel,
                             float* __restrict__ Wqkv, float* __restrict__ bqkv)
{
  int l = blockIdx.x;
  const float* wq = Wq + l * 4096; const float* wk = Wk + l * 4096; const float* wv = Wv + l * 4096;
  const float* bql = bq + l * 64;  const float* bkl = bk + l * 64;  const float* bvl = bv + l * 64;
  const float* ar = a_rel + l * 1024; const float* mr = m_rel + l * 1024;
  float* W = Wqkv + l * 64 * 192;  float* B = bqkv + l * 192;
  for (int t = threadIdx.x; t < 64 * 192; t += blockDim.x) {
    int i = t / 192, c = t % 192;
    float val;
    if (c < 64) {
      val = wq[i * 64 + c];
    } else if (c < 128) {
      int cc = c - 64, hh = cc >> 4, f = cc & 15;
      float s = 0.f;
      for (int d = 0; d < 16; ++d) s += wk[i * 64 + hh * 16 + d] * ar[hh * 256 + d * 16 + f];
      val = s;
    } else {
      int cc = c - 128, hh = cc >> 4, f = cc & 15;
      float s = 0.f;
      for (int d = 0; d < 16; ++d) s += wv[i * 64 + hh * 16 + d] * mr[hh * 256 + d * 16 + f];
      val = s;
    }
    W[i * 192 + c] = val;
  }
  for (int c = threadIdx.x; c < 192; c += blockDim.x) {
    float val;
    if (c < 64) {
      val = bql[c];
    } else if (c < 128) {
      int cc = c - 64, hh = cc >> 4, f = cc & 15;
      float s = 0.f;
      for (int d = 0; d < 16; ++d) s += bkl[hh * 16 + d] * ar[hh * 256 + d * 16 + f];
      val = s;
    } else {
      int cc = c - 128, hh = cc >> 4, f = cc & 15;
      float s = 0.f;
      for (int d = 0; d < 16; ++d) s += bvl[hh * 16 + d] * mr[hh * 256 + d * 16 + f];
      val = s;
    }
    B[c] = val;
  }
}

// ---------------- CSR construction -------------------------------------------
__global__ void hist_kernel(const int* __restrict__ dst, int* __restrict__ counts, int E) {
  int e = blockIdx.x * 256 + threadIdx.x;
  if (e < E) atomicAdd(&counts[dst[e]], 1);
}

__global__ __launch_bounds__(256)
void scanA(int* __restrict__ counts, int* __restrict__ blockSums, int n) {
  __shared__ int sd[256];
  int tid = threadIdx.x;
  int base = blockIdx.x * 1024 + tid * 4;
  int v[4];
#pragma unroll
  for (int j = 0; j < 4; ++j) v[j] = (base + j < n) ? counts[base + j] : 0;
  int t = v[0] + v[1] + v[2] + v[3];
  sd[tid] = t; __syncthreads();
  for (int offm = 1; offm < 256; offm <<= 1) {
    int adj = (tid >= offm) ? sd[tid - offm] : 0;
    __syncthreads();
    sd[tid] += adj;
    __syncthreads();
  }
  int run = sd[tid] - t;  // exclusive prefix for this thread
#pragma unroll
  for (int j = 0; j < 4; ++j) {
    if (base + j < n) counts[base + j] = run;
    run += v[j];
  }
  if (tid == 255) blockSums[blockIdx.x] = sd[255];
}

__global__ void scanB(int* __restrict__ blockSums, int G, int* __restrict__ row_ptr, int n) {
  __shared__ int sd[128];
  int tid = threadIdx.x;
  int t = (tid < G) ? blockSums[tid] : 0;
  sd[tid] = t; __syncthreads();
  for (int offm = 1; offm < 128; offm <<= 1) {
    int adj = (tid >= offm) ? sd[tid - offm] : 0;
    __syncthreads();
    sd[tid] += adj;
    __syncthreads();
  }
  if (tid < G) blockSums[tid] = sd[tid] - t;
  if (tid == 127) row_ptr[n] = sd[127];  // total = E
}

__global__ void scanC(const int* __restrict__ counts, const int* __restrict__ blockSums,
                      int* __restrict__ row_ptr, int* __restrict__ cursor, int n) {
  int idx = blockIdx.x * 256 + threadIdx.x;
  if (idx < n) {
    int v = counts[idx] + blockSums[idx >> 10];
    row_ptr[idx] = v;
    cursor[idx] = v;
  }
}

__global__ void scatter_kernel(const int* __restrict__ src, const int* __restrict__ dst,
                               int* __restrict__ cursor, int* __restrict__ csr_src, int E) {
  int e = blockIdx.x * 256 + threadIdx.x;
  if (e < E) {
    int d = dst[e];
    int pos = atomicAdd(&cursor[d], 1);
    csr_src[pos] = src[e];
  }
}

// ---------------- fused attention aggregation: one wave per dst node ----------
// lane = head*16 + f. qkv row layout: [q(64) | kt(64) | vt(64)], ld=192.
__global__ __launch_bounds__(256)
void edge_agg(const float* __restrict__ qkv, const int* __restrict__ row_ptr,
              const int* __restrict__ csr_src, const float* __restrict__ p_rel,
              float* __restrict__ agg, int n)
{
  int wid = blockIdx.x * 4 + (threadIdx.x >> 6);
  if (wid >= n) return;
  int lane = threadIdx.x & 63;
  int head = lane >> 4;
  float pr = p_rel[head] * 0.25f;  // p_rel / sqrt(D), D=16
  float qv = qkv[(size_t)wid * 192 + lane];
  int e0 = row_ptr[wid], e1 = row_ptr[wid + 1];
  float num = 0.f, den = 0.f;
  for (int e = e0; e < e1; ++e) {
    int s = csr_src[e];
    const float* base = qkv + (size_t)s * 192;
    float ktv = base[64 + lane];
    float vtv = base[128 + lane];
    float p = ktv * qv;
    p += __shfl_xor(p, 1);
    p += __shfl_xor(p, 2);
    p += __shfl_xor(p, 4);
    p += __shfl_xor(p, 8);   // per-head dot over 16 lanes
    float w = __expf(p * pr);
    den += w;
    num = fmaf(w, vtv, num);
  }
  agg[(size_t)wid * 64 + lane] = num / (den + 1e-16f);
}

// ---------------- classifier: 64 -> relu(32) -> 2 ----------------------------
__global__ __launch_bounds__(256)
void classifier(const float* __restrict__ h, const float* __restrict__ Wc1,
                const float* __restrict__ bc1, const float* __restrict__ Wc2,
                const float* __restrict__ bc2, float* __restrict__ out, int n)
{
  int row = blockIdx.x * 256 + threadIdx.x;
  if (row >= n) return;
  float hid[32];
#pragma unroll
  for (int j = 0; j < 32; ++j) hid[j] = bc1[j];
  const float* hr = h + (size_t)row * 64;
#pragma unroll
  for (int k = 0; k < 64; k += 4) {
    float4 x = *(const float4*)&hr[k];
#pragma unroll
    for (int j = 0; j < 32; ++j) {
      hid[j] += x.x * Wc1[k * 32 + j] + x.y * Wc1[(k + 1) * 32 + j]
              + x.z * Wc1[(k + 2) * 32 + j] + x.w * Wc1[(k + 3) * 32 + j];
    }
  }
  float o0 = bc2[0], o1 = bc2[1];
#pragma unroll
  for (int j = 0; j < 32; ++j) {
    float v = fmaxf(hid[j], 0.f);
    o0 += v * Wc2[j * 2 + 0];
    o1 += v * Wc2[j * 2 + 1];
  }
  *(float2*)&out[(size_t)row * 2] = make_float2(o0, o1);
}

// ---------------------------------------------------------------------------
extern "C" void kernel_launch(void* const* d_in, const int* in_sizes, int n_in,
                              void* d_out, int out_size, void* d_ws, size_t ws_size,
                              hipStream_t stream)
{
  const float* x     = (const float*)d_in[0];
  const int*  eidx   = (const int*)d_in[1];
  const float* Wp    = (const float*)d_in[2];
  const float* bp    = (const float*)d_in[3];
  const float* Wk    = (const float*)d_in[4];
  const float* bk    = (const float*)d_in[5];
  const float* Wq    = (const float*)d_in[6];
  const float* bq    = (const float*)d_in[7];
  const float* Wv    = (const float*)d_in[8];
  const float* bv    = (const float*)d_in[9];
  const float* a_rel = (const float*)d_in[10];
  const float* m_rel = (const float*)d_in[11];
  const float* p_rel = (const float*)d_in[12];
  const float* Wo    = (const float*)d_in[13];
  const float* bo    = (const float*)d_in[14];
  const float* skip  = (const float*)d_in[15];
  const float* Wc1   = (const float*)d_in[16];
  const float* bc1   = (const float*)d_in[17];
  const float* Wc2   = (const float*)d_in[18];
  const float* bc2   = (const float*)d_in[19];
  float* out = (float*)d_out;

  const int N = in_sizes[0] / 768;
  const int E = in_sizes[1] / 2;
  const int* srcIdx = eidx;
  const int* dstIdx = eidx + E;

  char* ws = (char*)d_ws;
  size_t off = 0;
  auto alloc = [&](size_t bytes) -> void* {
    void* p = ws + off;
    off = (off + bytes + 255) & ~(size_t)255;
    return p;
  };
  float* h     = (float*)alloc((size_t)N * 64 * 4);
  float* qkv   = (float*)alloc((size_t)N * 192 * 4);
  float* agg   = (float*)alloc((size_t)N * 64 * 4);
  float* Wqkv  = (float*)alloc(2 * 64 * 192 * 4);
  float* bqkv  = (float*)alloc(2 * 192 * 4);
  int* row_ptr = (int*)alloc((size_t)(N + 1) * 4);
  int* cursor  = (int*)alloc((size_t)N * 4);
  int* counts  = (int*)alloc((size_t)N * 4);
  int* blockSums = (int*)alloc(512 * 4);
  int* csr_src = (int*)alloc((size_t)E * 4);
  (void)ws_size; (void)n_in; (void)out_size;

  hipMemsetAsync(counts, 0, (size_t)N * 4, stream);

  fold_weights<<<2, 256, 0, stream>>>(Wq, bq, Wk, bk, Wv, bv, a_rel, m_rel, Wqkv, bqkv);

  // input projection: h = x @ Wp + bp   (no relu)
  gemm_tile<768, false, false><<<dim3((N + 127) / 128, 1), 256, 0, stream>>>(
      x, 768, Wp, 64, bp, nullptr, nullptr, h, 64, N);

  // CSR build (shared by both layers)
  hist_kernel<<<(E + 255) / 256, 256, 0, stream>>>(dstIdx, counts, E);
  int G = (N + 1023) / 1024;
  scanA<<<G, 256, 0, stream>>>(counts, blockSums, N);
  scanB<<<1, 128, 0, stream>>>(blockSums, G, row_ptr, N);
  scanC<<<(N + 255) / 256, 256, 0, stream>>>(counts, blockSums, row_ptr, cursor, N);
  scatter_kernel<<<(E + 255) / 256, 256, 0, stream>>>(srcIdx, dstIdx, cursor, csr_src, E);

  for (int l = 0; l < 2; ++l) {
    // fused q | kt | vt projection: [N,64] @ [64,192]
    gemm_tile<64, false, false><<<dim3((N + 127) / 128, 3), 256, 0, stream>>>(
        h, 64, Wqkv + l * 64 * 192, 192, bqkv + l * 192, nullptr, nullptr, qkv, 192, N);
    // attention + aggregation
    edge_agg<<<(N + 3) / 4, 256, 0, stream>>>(qkv, row_ptr, csr_src, p_rel + l * 4, agg, N);
    // out = relu(g*(gelu(agg)@Wo + bo) + (1-g)*h), in-place into h
    gemm_tile<64, true, true><<<dim3((N + 127) / 128, 1), 256, 0, stream>>>(
        agg, 64, Wo + l * 4096, 64, bo + l * 64, h, skip + l, h, 64, N);
  }

  classifier<<<(N + 255) / 256, 256, 0, stream>>>(h, Wc1, bc1, Wc2, bc2, out, N);
}

// Round 3
// 1326.062 us; speedup vs baseline: 4.0075x; 4.0075x over previous
//
#include <hip/hip_runtime.h>
#include <math.h>

// ---------------------------------------------------------------------------
// SimpleLESS4FDModel: 2-layer HGT on a homogeneous graph.
// Algebraic simplification: a_rel / m_rel are per-head linear transforms of
// k / v, folded into the projection weights (see fold_weights).
// Per edge:  alpha = <kt[src], q[dst]>_head * p_rel / 4 ;
//   agg[dst] = sum_e exp(alpha) * vt[src] / (sum_e exp(alpha) + 1e-16)
// CSR (built once, reused by both layers) makes aggregation atomic-free.
//
// R1 lesson: no runtime-indexed local arrays (forces scratch).
// R2 lesson: the fully-unrolled k=0..63 inner loop (192 ds_reads + 2048 FMAs
// straight-line) exploded live ranges -> 256 VGPRs + ~1.2 GB spill traffic.
// Fix: bounded unroll (x4) + unroll(disable) on the kc loop +
// __launch_bounds__(256,4) to cap the allocator at 128 VGPRs.
// ---------------------------------------------------------------------------

__device__ __forceinline__ float gelu_t(float x) {
  const float c = 0.7978845608028654f;  // sqrt(2/pi)
  float t = tanhf(c * (x + 0.044715f * x * x * x));
  return 0.5f * x * (1.0f + t);
}

// ---------------- tiled GEMM: 128 rows x 64 cols per block --------------------
// out[r, colBlk+c] = epi(A[r,:]@W[:,colBlk+c] + bias[colBlk+c])
// PRE_GELU: apply gelu to A elements when staging. EPI_SKIP: skip-mix + relu.
template<int K, bool PRE_GELU, bool EPI_SKIP>
__global__ __launch_bounds__(256, 4)   // cap VGPRs at 128: 4 waves/EU
void gemm_tile(const float* __restrict__ A, int ldA,
               const float* __restrict__ W, int ldW,
               const float* __restrict__ bias,
               const float* __restrict__ Hprev,
               const float* __restrict__ skipPtr,
               float* __restrict__ outp, int ldOut,
               int nRows)
{
  __shared__ float sA[64][132];  // [k][row] transposed; stride 132 keeps 16B align
  __shared__ float sB[64][68];   // [k][col]
  const int tid = threadIdx.x;
  const int ty = tid >> 4, tx = tid & 15;  // ty: 8 rows each, tx: 4 cols each
  const int row0 = blockIdx.x * 128;
  const int colBlk = blockIdx.y * 64;
  float acc[8][4];
#pragma unroll
  for (int i = 0; i < 8; ++i)
#pragma unroll
    for (int j = 0; j < 4; ++j) acc[i][j] = 0.f;

#pragma clang loop unroll(disable)
  for (int kc = 0; kc < K; kc += 64) {
    // stage A chunk (128 rows x 64 k), transposed into sA[k][row].
#pragma unroll
    for (int i = 0; i < 8; ++i) {
      int linear = i * 256 + tid;
      int r = linear >> 4;
      int k4 = (linear & 15) << 2;
      int gr = row0 + r;
      float4 v = make_float4(0.f, 0.f, 0.f, 0.f);
      if (gr < nRows) v = *(const float4*)(A + (size_t)gr * ldA + kc + k4);
      if (PRE_GELU) { v.x = gelu_t(v.x); v.y = gelu_t(v.y); v.z = gelu_t(v.z); v.w = gelu_t(v.w); }
      sA[k4 + 0][r] = v.x;
      sA[k4 + 1][r] = v.y;
      sA[k4 + 2][r] = v.z;
      sA[k4 + 3][r] = v.w;
    }
    // stage W chunk (64 k x 64 cols)
#pragma unroll
    for (int i = 0; i < 4; ++i) {
      int linear = i * 256 + tid;
      int kk = linear >> 4;
      int c4 = (linear & 15) << 2;
      *(float4*)&sB[kk][c4] = *(const float4*)(W + (size_t)(kc + kk) * ldW + colBlk + c4);
    }
    __syncthreads();
    // bounded unroll: 12 ds_read_b128 + 128 FMAs per group keeps VGPR
    // pressure ~100 (full unroll spilled -- R2 lesson).
#pragma unroll 4
    for (int k = 0; k < 64; ++k) {
      float4 b4 = *(const float4*)&sB[k][tx << 2];
      float4 a0 = *(const float4*)&sA[k][ty << 3];
      float4 a1 = *(const float4*)&sA[k][(ty << 3) + 4];
      float aa[8] = {a0.x, a0.y, a0.z, a0.w, a1.x, a1.y, a1.z, a1.w};
      float bb[4] = {b4.x, b4.y, b4.z, b4.w};
#pragma unroll
      for (int i = 0; i < 8; ++i)
#pragma unroll
        for (int j = 0; j < 4; ++j)
          acc[i][j] = fmaf(aa[i], bb[j], acc[i][j]);
    }
    __syncthreads();
  }

  float g = 0.f, gi = 0.f;
  if (EPI_SKIP) { g = 1.0f / (1.0f + __expf(-skipPtr[0])); gi = 1.0f - g; }
  float4 bia = *(const float4*)(bias + colBlk + (tx << 2));
  float bb[4] = {bia.x, bia.y, bia.z, bia.w};
#pragma unroll
  for (int i = 0; i < 8; ++i) {
    int r = row0 + (ty << 3) + i;
    if (r < nRows) {
      float o[4];
#pragma unroll
      for (int j = 0; j < 4; ++j) o[j] = acc[i][j] + bb[j];
      if (EPI_SKIP) {
        float4 hp = *(const float4*)(Hprev + (size_t)r * 64 + (tx << 2));
        float hh[4] = {hp.x, hp.y, hp.z, hp.w};
#pragma unroll
        for (int j = 0; j < 4; ++j) o[j] = fmaxf(g * o[j] + gi * hh[j], 0.f);
      }
      float4 ov = make_float4(o[0], o[1], o[2], o[3]);
      *(float4*)(outp + (size_t)r * ldOut + colBlk + (tx << 2)) = ov;
    }
  }
}

// ---------------- fold a_rel / m_rel into packed qkv weights ------------------
// Wqkv[l]: [64][192]  cols 0..63 = Wq, 64..127 = Wk@BD(a_rel), 128..191 = Wv@BD(m_rel)
__global__ void fold_weights(const float* __restrict__ Wq, const float* __restrict__ bq,
                             const float* __restrict__ Wk, const float* __restrict__ bk,
                             const float* __restrict__ Wv, const float* __restrict__ bv,
                             const float* __restrict__ a_rel, const float* __restrict__ m_rel,
                             float* __restrict__ Wqkv, float* __restrict__ bqkv)
{
  int l = blockIdx.x;
  const float* wq = Wq + l * 4096; const float* wk = Wk + l * 4096; const float* wv = Wv + l * 4096;
  const float* bql = bq + l * 64;  const float* bkl = bk + l * 64;  const float* bvl = bv + l * 64;
  const float* ar = a_rel + l * 1024; const float* mr = m_rel + l * 1024;
  float* W = Wqkv + l * 64 * 192;  float* B = bqkv + l * 192;
  for (int t = threadIdx.x; t < 64 * 192; t += blockDim.x) {
    int i = t / 192, c = t % 192;
    float val;
    if (c < 64) {
      val = wq[i * 64 + c];
    } else if (c < 128) {
      int cc = c - 64, hh = cc >> 4, f = cc & 15;
      float s = 0.f;
      for (int d = 0; d < 16; ++d) s += wk[i * 64 + hh * 16 + d] * ar[hh * 256 + d * 16 + f];
      val = s;
    } else {
      int cc = c - 128, hh = cc >> 4, f = cc & 15;
      float s = 0.f;
      for (int d = 0; d < 16; ++d) s += wv[i * 64 + hh * 16 + d] * mr[hh * 256 + d * 16 + f];
      val = s;
    }
    W[i * 192 + c] = val;
  }
  for (int c = threadIdx.x; c < 192; c += blockDim.x) {
    float val;
    if (c < 64) {
      val = bql[c];
    } else if (c < 128) {
      int cc = c - 64, hh = cc >> 4, f = cc & 15;
      float s = 0.f;
      for (int d = 0; d < 16; ++d) s += bkl[hh * 16 + d] * ar[hh * 256 + d * 16 + f];
      val = s;
    } else {
      int cc = c - 128, hh = cc >> 4, f = cc & 15;
      float s = 0.f;
      for (int d = 0; d < 16; ++d) s += bvl[hh * 16 + d] * mr[hh * 256 + d * 16 + f];
      val = s;
    }
    B[c] = val;
  }
}

// ---------------- CSR construction -------------------------------------------
__global__ void hist_kernel(const int* __restrict__ dst, int* __restrict__ counts, int E) {
  int e = blockIdx.x * 256 + threadIdx.x;
  if (e < E) atomicAdd(&counts[dst[e]], 1);
}

__global__ __launch_bounds__(256)
void scanA(int* __restrict__ counts, int* __restrict__ blockSums, int n) {
  __shared__ int sd[256];
  int tid = threadIdx.x;
  int base = blockIdx.x * 1024 + tid * 4;
  int v[4];
#pragma unroll
  for (int j = 0; j < 4; ++j) v[j] = (base + j < n) ? counts[base + j] : 0;
  int t = v[0] + v[1] + v[2] + v[3];
  sd[tid] = t; __syncthreads();
  for (int offm = 1; offm < 256; offm <<= 1) {
    int adj = (tid >= offm) ? sd[tid - offm] : 0;
    __syncthreads();
    sd[tid] += adj;
    __syncthreads();
  }
  int run = sd[tid] - t;  // exclusive prefix for this thread
#pragma unroll
  for (int j = 0; j < 4; ++j) {
    if (base + j < n) counts[base + j] = run;
    run += v[j];
  }
  if (tid == 255) blockSums[blockIdx.x] = sd[255];
}

__global__ void scanB(int* __restrict__ blockSums, int G, int* __restrict__ row_ptr, int n) {
  __shared__ int sd[128];
  int tid = threadIdx.x;
  int t = (tid < G) ? blockSums[tid] : 0;
  sd[tid] = t; __syncthreads();
  for (int offm = 1; offm < 128; offm <<= 1) {
    int adj = (tid >= offm) ? sd[tid - offm] : 0;
    __syncthreads();
    sd[tid] += adj;
    __syncthreads();
  }
  if (tid < G) blockSums[tid] = sd[tid] - t;
  if (tid == 127) row_ptr[n] = sd[127];  // total = E
}

__global__ void scanC(const int* __restrict__ counts, const int* __restrict__ blockSums,
                      int* __restrict__ row_ptr, int* __restrict__ cursor, int n) {
  int idx = blockIdx.x * 256 + threadIdx.x;
  if (idx < n) {
    int v = counts[idx] + blockSums[idx >> 10];
    row_ptr[idx] = v;
    cursor[idx] = v;
  }
}

__global__ void scatter_kernel(const int* __restrict__ src, const int* __restrict__ dst,
                               int* __restrict__ cursor, int* __restrict__ csr_src, int E) {
  int e = blockIdx.x * 256 + threadIdx.x;
  if (e < E) {
    int d = dst[e];
    int pos = atomicAdd(&cursor[d], 1);
    csr_src[pos] = src[e];
  }
}

// ---------------- fused attention aggregation: one wave per dst node ----------
// lane = head*16 + f. qkv row layout: [q(64) | kt(64) | vt(64)], ld=192.
__global__ __launch_bounds__(256)
void edge_agg(const float* __restrict__ qkv, const int* __restrict__ row_ptr,
              const int* __restrict__ csr_src, const float* __restrict__ p_rel,
              float* __restrict__ agg, int n)
{
  int wid = blockIdx.x * 4 + (threadIdx.x >> 6);
  if (wid >= n) return;
  int lane = threadIdx.x & 63;
  int head = lane >> 4;
  float pr = p_rel[head] * 0.25f;  // p_rel / sqrt(D), D=16
  float qv = qkv[(size_t)wid * 192 + lane];
  int e0 = row_ptr[wid], e1 = row_ptr[wid + 1];
  float num = 0.f, den = 0.f;
  for (int e = e0; e < e1; ++e) {
    int s = csr_src[e];
    const float* base = qkv + (size_t)s * 192;
    float ktv = base[64 + lane];
    float vtv = base[128 + lane];
    float p = ktv * qv;
    p += __shfl_xor(p, 1);
    p += __shfl_xor(p, 2);
    p += __shfl_xor(p, 4);
    p += __shfl_xor(p, 8);   // per-head dot over 16 lanes
    float w = __expf(p * pr);
    den += w;
    num = fmaf(w, vtv, num);
  }
  agg[(size_t)wid * 64 + lane] = num / (den + 1e-16f);
}

// ---------------- classifier: 64 -> relu(32) -> 2 ----------------------------
__global__ __launch_bounds__(256)
void classifier(const float* __restrict__ h, const float* __restrict__ Wc1,
                const float* __restrict__ bc1, const float* __restrict__ Wc2,
                const float* __restrict__ bc2, float* __restrict__ out, int n)
{
  int row = blockIdx.x * 256 + threadIdx.x;
  if (row >= n) return;
  float hid[32];
#pragma unroll
  for (int j = 0; j < 32; ++j) hid[j] = bc1[j];
  const float* hr = h + (size_t)row * 64;
#pragma unroll 4
  for (int k = 0; k < 64; k += 4) {
    float4 x = *(const float4*)&hr[k];
#pragma unroll
    for (int j = 0; j < 32; ++j) {
      hid[j] += x.x * Wc1[k * 32 + j] + x.y * Wc1[(k + 1) * 32 + j]
              + x.z * Wc1[(k + 2) * 32 + j] + x.w * Wc1[(k + 3) * 32 + j];
    }
  }
  float o0 = bc2[0], o1 = bc2[1];
#pragma unroll
  for (int j = 0; j < 32; ++j) {
    float v = fmaxf(hid[j], 0.f);
    o0 += v * Wc2[j * 2 + 0];
    o1 += v * Wc2[j * 2 + 1];
  }
  *(float2*)&out[(size_t)row * 2] = make_float2(o0, o1);
}

// ---------------------------------------------------------------------------
extern "C" void kernel_launch(void* const* d_in, const int* in_sizes, int n_in,
                              void* d_out, int out_size, void* d_ws, size_t ws_size,
                              hipStream_t stream)
{
  const float* x     = (const float*)d_in[0];
  const int*  eidx   = (const int*)d_in[1];
  const float* Wp    = (const float*)d_in[2];
  const float* bp    = (const float*)d_in[3];
  const float* Wk    = (const float*)d_in[4];
  const float* bk    = (const float*)d_in[5];
  const float* Wq    = (const float*)d_in[6];
  const float* bq    = (const float*)d_in[7];
  const float* Wv    = (const float*)d_in[8];
  const float* bv    = (const float*)d_in[9];
  const float* a_rel = (const float*)d_in[10];
  const float* m_rel = (const float*)d_in[11];
  const float* p_rel = (const float*)d_in[12];
  const float* Wo    = (const float*)d_in[13];
  const float* bo    = (const float*)d_in[14];
  const float* skip  = (const float*)d_in[15];
  const float* Wc1   = (const float*)d_in[16];
  const float* bc1   = (const float*)d_in[17];
  const float* Wc2   = (const float*)d_in[18];
  const float* bc2   = (const float*)d_in[19];
  float* out = (float*)d_out;

  const int N = in_sizes[0] / 768;
  const int E = in_sizes[1] / 2;
  const int* srcIdx = eidx;
  const int* dstIdx = eidx + E;

  char* ws = (char*)d_ws;
  size_t off = 0;
  auto alloc = [&](size_t bytes) -> void* {
    void* p = ws + off;
    off = (off + bytes + 255) & ~(size_t)255;
    return p;
  };
  float* h     = (float*)alloc((size_t)N * 64 * 4);
  float* qkv   = (float*)alloc((size_t)N * 192 * 4);
  float* agg   = (float*)alloc((size_t)N * 64 * 4);
  float* Wqkv  = (float*)alloc(2 * 64 * 192 * 4);
  float* bqkv  = (float*)alloc(2 * 192 * 4);
  int* row_ptr = (int*)alloc((size_t)(N + 1) * 4);
  int* cursor  = (int*)alloc((size_t)N * 4);
  int* counts  = (int*)alloc((size_t)N * 4);
  int* blockSums = (int*)alloc(512 * 4);
  int* csr_src = (int*)alloc((size_t)E * 4);
  (void)ws_size; (void)n_in; (void)out_size;

  hipMemsetAsync(counts, 0, (size_t)N * 4, stream);

  fold_weights<<<2, 256, 0, stream>>>(Wq, bq, Wk, bk, Wv, bv, a_rel, m_rel, Wqkv, bqkv);

  // input projection: h = x @ Wp + bp   (no relu)
  gemm_tile<768, false, false><<<dim3((N + 127) / 128, 1), 256, 0, stream>>>(
      x, 768, Wp, 64, bp, nullptr, nullptr, h, 64, N);

  // CSR build (shared by both layers)
  hist_kernel<<<(E + 255) / 256, 256, 0, stream>>>(dstIdx, counts, E);
  int G = (N + 1023) / 1024;
  scanA<<<G, 256, 0, stream>>>(counts, blockSums, N);
  scanB<<<1, 128, 0, stream>>>(blockSums, G, row_ptr, N);
  scanC<<<(N + 255) / 256, 256, 0, stream>>>(counts, blockSums, row_ptr, cursor, N);
  scatter_kernel<<<(E + 255) / 256, 256, 0, stream>>>(srcIdx, dstIdx, cursor, csr_src, E);

  for (int l = 0; l < 2; ++l) {
    // fused q | kt | vt projection: [N,64] @ [64,192]
    gemm_tile<64, false, false><<<dim3((N + 127) / 128, 3), 256, 0, stream>>>(
        h, 64, Wqkv + l * 64 * 192, 192, bqkv + l * 192, nullptr, nullptr, qkv, 192, N);
    // attention + aggregation
    edge_agg<<<(N + 3) / 4, 256, 0, stream>>>(qkv, row_ptr, csr_src, p_rel + l * 4, agg, N);
    // out = relu(g*(gelu(agg)@Wo + bo) + (1-g)*h), in-place into h
    gemm_tile<64, true, true><<<dim3((N + 127) / 128, 1), 256, 0, stream>>>(
        agg, 64, Wo + l * 4096, 64, bo + l * 64, h, skip + l, h, 64, N);
  }

  classifier<<<(N + 255) / 256, 256, 0, stream>>>(h, Wc1, bc1, Wc2, bc2, out, N);
}